// Round 7
// baseline (1730.786 us; speedup 1.0000x reference)
//
#include <hip/hip_runtime.h>
#include <hip/hip_cooperative_groups.h>
#include <math.h>

namespace cg = cooperative_groups;

#define BATCH 2
#define TSTEPS 8

typedef __attribute__((ext_vector_type(8))) short s16x8;   // 8 bf16 (4 VGPRs)
typedef __attribute__((ext_vector_type(4))) float f32x4;   // MFMA accum

__device__ __forceinline__ float hsig(float v){ return fminf(fmaxf(0.2f*v+0.5f,0.f),1.f); }

__device__ __forceinline__ ushort f2bf(float f){
    uint u = __builtin_bit_cast(uint, f);
    u = (u + 0x7FFFu + ((u >> 16) & 1u)) >> 16;   // round-to-nearest-even
    return (ushort)u;
}

// ---------------- fused prep: x cast + 6 gate-interleaved weight transposes ----
template<int K,int N,int Co>
__device__ __forceinline__ void transw1(const float* __restrict__ W, ushort* __restrict__ Wt, int j){
    int n = j / K, k = j - n * K;
    int g = n & 3, co = n >> 2;            // dest row n' = co*4+g
    Wt[j] = f2bf(W[(size_t)k * N + g * Co + co]);
}

#define SZ_X    786432
#define SZ_WX1  884736
#define SZ_WH1  589824
#define SZ_WX2  294912
#define SZ_WH2  147456
#define SZ_WX3  73728
#define SZ_WH3  36864
#define SZ_PREP (SZ_X+SZ_WX1+SZ_WH1+SZ_WX2+SZ_WH2+SZ_WX3+SZ_WH3)

__global__ void prep_kernel(const float* __restrict__ x,
    const float* __restrict__ Wx1, const float* __restrict__ Wh1,
    const float* __restrict__ Wx2, const float* __restrict__ Wh2,
    const float* __restrict__ Wx3, const float* __restrict__ Wh3,
    ushort* __restrict__ xbf,
    ushort* __restrict__ Wxt1, ushort* __restrict__ Wht1,
    ushort* __restrict__ Wxt2, ushort* __restrict__ Wht2,
    ushort* __restrict__ Wxt3, ushort* __restrict__ Wht3)
{
    int i = blockIdx.x * 256 + threadIdx.x;
    if (i < SZ_X){ xbf[i] = f2bf(x[i]); return; } i -= SZ_X;
    if (i < SZ_WX1){ transw1<1728,512,128>(Wx1, Wxt1, i); return; } i -= SZ_WX1;
    if (i < SZ_WH1){ transw1<1152,512,128>(Wh1, Wht1, i); return; } i -= SZ_WH1;
    if (i < SZ_WX2){ transw1<1152,256, 64>(Wx2, Wxt2, i); return; } i -= SZ_WX2;
    if (i < SZ_WH2){ transw1< 576,256, 64>(Wh2, Wht2, i); return; } i -= SZ_WH2;
    if (i < SZ_WX3){ transw1< 576,128, 32>(Wx3, Wxt3, i); return; } i -= SZ_WX3;
    if (i < SZ_WH3){ transw1< 288,128, 32>(Wh3, Wht3, i); }
}

// ---------------------------------------------------------------------------
// convx: implicit-im2col GEMM, bf16 MFMA, no LDS/barriers. 64x64 wg tile,
// 4 waves of 32x32 (2x2 MFMA frags) -> 4x the workgroups of the 128-tile.
// Zx out fp32 [M][N'] gate-interleaved (n' = co*4+g), bias added.
// ---------------------------------------------------------------------------
template<int CI, int CO>
__global__ __launch_bounds__(256) void convx_mfma(
    const ushort* __restrict__ Abf, const ushort* __restrict__ Wt,
    const float* __restrict__ bias, float* __restrict__ Zx,
    int H, int Wd)
{
    constexpr int K = 9 * CI;
    constexpr int N = 4 * CO;

    const int tid = threadIdx.x;
    const int m0 = blockIdx.x * 64, n0 = blockIdx.y * 64;
    const int lane = tid & 63, wave = tid >> 6;
    const int wm = wave >> 1, wn = wave & 1;
    const int quad = lane >> 4, l16 = lane & 15;
    const int HW = H * Wd;

    int py[2], px[2], pbt[2];
    #pragma unroll
    for (int mt = 0; mt < 2; ++mt){
        const int p = m0 + wm * 32 + mt * 16 + l16;
        pbt[mt] = p / HW;
        const int rem = p - pbt[mt] * HW;
        py[mt] = rem / Wd; px[mt] = rem - (rem / Wd) * Wd;
    }
    const ushort* bp[2];
    #pragma unroll
    for (int nt = 0; nt < 2; ++nt)
        bp[nt] = &Wt[(size_t)(n0 + wn * 32 + nt * 16 + l16) * K + quad * 8];

    f32x4 acc[2][2] = {};

    #pragma unroll
    for (int tap = 0; tap < 9; ++tap){
        const int kh = tap / 3, kw = tap - (tap / 3) * 3;
        const ushort* ap[2]; bool va[2];
        #pragma unroll
        for (int mt = 0; mt < 2; ++mt){
            const int yy = py[mt] + kh - 1, xx = px[mt] + kw - 1;
            va[mt] = (yy >= 0 && yy < H && xx >= 0 && xx < Wd);
            ap[mt] = &Abf[((size_t)(pbt[mt] * H + (va[mt] ? yy : 0)) * Wd + (va[mt] ? xx : 0)) * CI + quad * 8];
        }
        #pragma unroll
        for (int ci0 = 0; ci0 < CI; ci0 += 32){
            s16x8 af[2], bf2[2];
            #pragma unroll
            for (int mt = 0; mt < 2; ++mt){
                s16x8 v = *(const s16x8*)(ap[mt] + ci0);
                af[mt] = va[mt] ? v : (s16x8)0;
            }
            #pragma unroll
            for (int nt = 0; nt < 2; ++nt)
                bf2[nt] = *(const s16x8*)(bp[nt] + tap * CI + ci0);
            #pragma unroll
            for (int mt = 0; mt < 2; ++mt)
                #pragma unroll
                for (int nt = 0; nt < 2; ++nt)
                    acc[mt][nt] = __builtin_amdgcn_mfma_f32_16x16x32_bf16(af[mt], bf2[nt], acc[mt][nt], 0, 0, 0);
        }
    }

    #pragma unroll
    for (int mt = 0; mt < 2; ++mt){
        #pragma unroll
        for (int nt = 0; nt < 2; ++nt){
            const int col = n0 + wn * 32 + nt * 16 + l16;      // interleaved col co*4+g
            const float bv = bias[(col & 3) * CO + (col >> 2)];
            #pragma unroll
            for (int r = 0; r < 4; ++r){
                const int row = m0 + wm * 32 + mt * 16 + quad * 4 + r;
                Zx[(size_t)row * N + col] = acc[mt][nt][r] + bv;
            }
        }
    }
}

// ---------------------------------------------------------------------------
// All 8 LSTM timesteps of one block in ONE cooperative kernel.
// Grid = 256 wgs (persistent); per t: each wg loops tiles of 32 pixels x 32
// interleaved ncols; K-loop SPLIT ACROSS THE 4 WAVES (LDS reduce in epilogue);
// grid.sync() between timesteps. t=0 skips conv (h0=0) and cst read (c0=0).
// ---------------------------------------------------------------------------
template<int CO, int OUT_BF16>
__global__ __launch_bounds__(256) void steps_coop(
    const float* __restrict__ Zx, const ushort* __restrict__ Wht,
    ushort* __restrict__ hA, ushort* __restrict__ hB, float* __restrict__ cst,
    const float* __restrict__ gamma, const float* __restrict__ beta,
    const float* __restrict__ mmean, const float* __restrict__ mvar,
    void* __restrict__ outp, int H, int Wd, int nTilesM, int nTilesN)
{
    constexpr int K = 9 * CO;
    constexpr int N4 = 4 * CO;
    constexpr int KITERS = K / 32;
    constexpr int CPT = CO / 32;   // k-chunks per tap

    cg::grid_group grid = cg::this_grid();
    __shared__ float Zs[4][32][36];   // per-wave K-partials (18.4 KB)

    const int tid = threadIdx.x, bid = blockIdx.x;
    const int lane = tid & 63, wave = tid >> 6;
    const int quad = lane >> 4, l16 = lane & 15;
    const int HW = H * Wd;
    const int nTiles = nTilesM * nTilesN;
    const int W2 = 2 * Wd;

    for (int t = 0; t < TSTEPS; ++t){
        const ushort* hprev = (t & 1) ? hB : hA;
        ushort* hnew = (t & 1) ? hA : hB;

        for (int tile = bid; tile < nTiles; tile += (int)gridDim.x){
            const int tm_ = tile / nTilesN, tn_ = tile - tm_ * nTilesN;
            const int m0 = tm_ * 32, n0 = tn_ * 32;

            f32x4 acc[2][2] = {};
            if (t > 0){
                int py[2], px[2], pb[2];
                #pragma unroll
                for (int mt = 0; mt < 2; ++mt){
                    const int p = m0 + mt * 16 + l16;
                    pb[mt] = p / HW;
                    const int rem = p - pb[mt] * HW;
                    py[mt] = rem / Wd; px[mt] = rem - (rem / Wd) * Wd;
                }
                const ushort* bp[2];
                #pragma unroll
                for (int nt = 0; nt < 2; ++nt)
                    bp[nt] = &Wht[(size_t)(n0 + nt * 16 + l16) * K + quad * 8];

                for (int it = wave; it < KITERS; it += 4){
                    const int tap = it / CPT;
                    const int ci0 = (it - tap * CPT) * 32;
                    const int kh = tap / 3, kw = tap - (tap / 3) * 3;
                    s16x8 af[2], bf2[2];
                    #pragma unroll
                    for (int mt = 0; mt < 2; ++mt){
                        const int yy = py[mt] + kh - 1, xx = px[mt] + kw - 1;
                        const bool va = (yy >= 0 && yy < H && xx >= 0 && xx < Wd);
                        s16x8 v = *(const s16x8*)&hprev[((size_t)(pb[mt] * H + (va ? yy : 0)) * Wd + (va ? xx : 0)) * CO + ci0 + quad * 8];
                        af[mt] = va ? v : (s16x8)0;
                    }
                    #pragma unroll
                    for (int nt = 0; nt < 2; ++nt)
                        bf2[nt] = *(const s16x8*)(bp[nt] + tap * CO + ci0);
                    #pragma unroll
                    for (int mt = 0; mt < 2; ++mt)
                        #pragma unroll
                        for (int nt = 0; nt < 2; ++nt)
                            acc[mt][nt] = __builtin_amdgcn_mfma_f32_16x16x32_bf16(af[mt], bf2[nt], acc[mt][nt], 0, 0, 0);
                }
            }

            // stash per-wave partials
            #pragma unroll
            for (int mt = 0; mt < 2; ++mt)
                #pragma unroll
                for (int nt = 0; nt < 2; ++nt)
                    #pragma unroll
                    for (int r = 0; r < 4; ++r)
                        Zs[wave][mt * 16 + quad * 4 + r][nt * 16 + l16] = acc[mt][nt][r];
            __syncthreads();

            // epilogue: 32 pixels x 8 co (one (pixel,co) per thread; 4 gates)
            {
                const int pp = tid >> 3, lc = tid & 7;
                const int m = m0 + pp;
                const int b2 = m / HW; const int rr = m - b2 * HW;
                const int y2 = rr / Wd, x2 = rr - (rr / Wd) * Wd;
                const int co = (n0 >> 2) + lc;

                const float4 s0 = *(const float4*)&Zs[0][pp][lc * 4];
                const float4 s1 = *(const float4*)&Zs[1][pp][lc * 4];
                const float4 s2 = *(const float4*)&Zs[2][pp][lc * 4];
                const float4 s3 = *(const float4*)&Zs[3][pp][lc * 4];

                const size_t zrow = (size_t)(b2 * TSTEPS + t) * HW + rr;
                const float4 zx = *(const float4*)&Zx[zrow * N4 + n0 + lc * 4];

                const float zi = s0.x + s1.x + s2.x + s3.x + zx.x;
                const float zf = s0.y + s1.y + s2.y + s3.y + zx.y;
                const float zg = s0.z + s1.z + s2.z + s3.z + zx.z;
                const float zo = s0.w + s1.w + s2.w + s3.w + zx.w;

                const float iv = hsig(zi), fv = hsig(zf);
                const float gv = tanhf(zg), ov = hsig(zo);
                const float cold = (t > 0) ? cst[(size_t)m * CO + co] : 0.0f;
                const float cn = fv * cold + iv * gv;
                cst[(size_t)m * CO + co] = cn;
                const float h = ov * tanhf(cn);
                hnew[(size_t)m * CO + co] = f2bf(h);

                const float bnv = (h - mmean[co]) * rsqrtf(mvar[co] + 1e-3f) * gamma[co] + beta[co];
                const size_t ob = ((size_t)(b2 * TSTEPS + t) * 2 * H + 2 * y2) * W2 + 2 * x2;
                if (OUT_BF16){
                    ushort* o = (ushort*)outp; const ushort hv = f2bf(bnv);
                    o[ob * CO + co] = hv; o[(ob + 1) * CO + co] = hv;
                    o[(ob + W2) * CO + co] = hv; o[(ob + W2 + 1) * CO + co] = hv;
                } else {
                    float* o = (float*)outp;
                    o[ob * CO + co] = bnv; o[(ob + 1) * CO + co] = bnv;
                    o[(ob + W2) * CO + co] = bnv; o[(ob + W2 + 1) * CO + co] = bnv;
                }
            }
            __syncthreads();
        }

        if (t + 1 < TSTEPS){
            __threadfence();
            grid.sync();
        }
    }
}

template<int CI, int CO, int OUT_BF16>
static void run_block(const ushort* xbf, const ushort* Wxt, const ushort* Wht, const float* bias,
                      const float* g, const float* be, const float* mm, const float* mv,
                      float* Zx, ushort* hA, ushort* hB, float* cbuf, void* out,
                      int H, int W, hipStream_t stream)
{
    const int M = BATCH * TSTEPS * H * W;
    dim3 gx(M / 64, (4 * CO) / 64);
    convx_mfma<CI, CO><<<gx, 256, 0, stream>>>(xbf, Wxt, bias, Zx, H, W);

    int nTilesM = (BATCH * H * W) / 32;
    int nTilesN = (4 * CO) / 32;
    int Hc = H, Wc = W;
    const float* Zxc = Zx;
    void* args[] = { (void*)&Zxc, (void*)&Wht, (void*)&hA, (void*)&hB, (void*)&cbuf,
                     (void*)&g, (void*)&be, (void*)&mm, (void*)&mv, (void*)&out,
                     (void*)&Hc, (void*)&Wc, (void*)&nTilesM, (void*)&nTilesN };
    auto kfn = steps_coop<CO, OUT_BF16>;
    hipLaunchCooperativeKernel(reinterpret_cast<void*>(kfn), dim3(256), dim3(256), args, 0, stream);
}

extern "C" void kernel_launch(void* const* d_in, const int* in_sizes, int n_in,
                              void* d_out, int out_size, void* d_ws, size_t ws_size,
                              hipStream_t stream) {
    const float* x   = (const float*)d_in[0];
    const float* Wx1 = (const float*)d_in[1];  const float* Wh1 = (const float*)d_in[2];
    const float* b1  = (const float*)d_in[3];  const float* g1  = (const float*)d_in[4];
    const float* be1 = (const float*)d_in[5];  const float* mm1 = (const float*)d_in[6];
    const float* mv1 = (const float*)d_in[7];
    const float* Wx2 = (const float*)d_in[8];  const float* Wh2 = (const float*)d_in[9];
    const float* b2  = (const float*)d_in[10]; const float* g2  = (const float*)d_in[11];
    const float* be2 = (const float*)d_in[12]; const float* mm2 = (const float*)d_in[13];
    const float* mv2 = (const float*)d_in[14];
    const float* Wx3 = (const float*)d_in[15]; const float* Wh3 = (const float*)d_in[16];
    const float* b3  = (const float*)d_in[17]; const float* g3  = (const float*)d_in[18];
    const float* be3 = (const float*)d_in[19]; const float* mm3 = (const float*)d_in[20];
    const float* mv3 = (const float*)d_in[21];

    char* ws = (char*)d_ws;
    size_t off = 0;
    auto alloc = [&](size_t bytes) { char* p = ws + off; off += (bytes + 255) & ~(size_t)255; return p; };

    float*  Zx   = (float*)alloc(8388608ull * 4);      // max Zx (block3: 65536*128)
    float*  cbuf = (float*)alloc(262144ull * 4);       // max c (block3: 8192*32)
    ushort* xbf  = (ushort*)alloc(786432ull * 2);
    ushort* x2   = (ushort*)alloc(2097152ull * 2);     // block1 out (bf16)
    ushort* x3   = (ushort*)alloc(4194304ull * 2);     // block2 out (bf16)
    ushort* hA   = (ushort*)alloc(262144ull * 2);
    ushort* hB   = (ushort*)alloc(262144ull * 2);
    ushort* Wxt1 = (ushort*)alloc(884736ull * 2);
    ushort* Wxt2 = (ushort*)alloc(294912ull * 2);
    ushort* Wxt3 = (ushort*)alloc(73728ull * 2);
    ushort* Wht1 = (ushort*)alloc(589824ull * 2);
    ushort* Wht2 = (ushort*)alloc(147456ull * 2);
    ushort* Wht3 = (ushort*)alloc(36864ull * 2);

    prep_kernel<<<(SZ_PREP + 255) / 256, 256, 0, stream>>>(
        x, Wx1, Wh1, Wx2, Wh2, Wx3, Wh3,
        xbf, Wxt1, Wht1, Wxt2, Wht2, Wxt3, Wht3);

    run_block<192, 128, 1>(xbf, Wxt1, Wht1, b1, g1, be1, mm1, mv1, Zx, hA, hB, cbuf, x2, 16, 16, stream);
    run_block<128,  64, 1>(x2,  Wxt2, Wht2, b2, g2, be2, mm2, mv2, Zx, hA, hB, cbuf, x3, 32, 32, stream);
    run_block< 64,  32, 0>(x3,  Wxt3, Wht3, b3, g3, be3, mm3, mv3, Zx, hA, hB, cbuf, d_out, 64, 64, stream);
}

// Round 8
// 459.479 us; speedup vs baseline: 3.7668x; 3.7668x over previous
//
#include <hip/hip_runtime.h>
#include <math.h>

#define BATCH 2
#define TSTEPS 8

typedef __attribute__((ext_vector_type(8))) short s16x8;   // 8 bf16 (4 VGPRs)
typedef __attribute__((ext_vector_type(4))) float f32x4;   // MFMA accum

__device__ __forceinline__ float hsig(float v){ return fminf(fmaxf(0.2f*v+0.5f,0.f),1.f); }

__device__ __forceinline__ ushort f2bf(float f){
    uint u = __builtin_bit_cast(uint, f);
    u = (u + 0x7FFFu + ((u >> 16) & 1u)) >> 16;   // round-to-nearest-even
    return (ushort)u;
}

// ---------------- fused prep: x cast + 6 gate-interleaved weight transposes ----
template<int K,int N,int Co>
__device__ __forceinline__ void transw1(const float* __restrict__ W, ushort* __restrict__ Wt, int j){
    int n = j / K, k = j - n * K;
    int g = n & 3, co = n >> 2;            // dest row n' = co*4+g
    Wt[j] = f2bf(W[(size_t)k * N + g * Co + co]);
}

#define SZ_X    786432
#define SZ_WX1  884736
#define SZ_WH1  589824
#define SZ_WX2  294912
#define SZ_WH2  147456
#define SZ_WX3  73728
#define SZ_WH3  36864
#define SZ_PREP (SZ_X+SZ_WX1+SZ_WH1+SZ_WX2+SZ_WH2+SZ_WX3+SZ_WH3)

__global__ void prep_kernel(const float* __restrict__ x,
    const float* __restrict__ Wx1, const float* __restrict__ Wh1,
    const float* __restrict__ Wx2, const float* __restrict__ Wh2,
    const float* __restrict__ Wx3, const float* __restrict__ Wh3,
    ushort* __restrict__ xbf,
    ushort* __restrict__ Wxt1, ushort* __restrict__ Wht1,
    ushort* __restrict__ Wxt2, ushort* __restrict__ Wht2,
    ushort* __restrict__ Wxt3, ushort* __restrict__ Wht3)
{
    int i = blockIdx.x * 256 + threadIdx.x;
    if (i < SZ_X){ xbf[i] = f2bf(x[i]); return; } i -= SZ_X;
    if (i < SZ_WX1){ transw1<1728,512,128>(Wx1, Wxt1, i); return; } i -= SZ_WX1;
    if (i < SZ_WH1){ transw1<1152,512,128>(Wh1, Wht1, i); return; } i -= SZ_WH1;
    if (i < SZ_WX2){ transw1<1152,256, 64>(Wx2, Wxt2, i); return; } i -= SZ_WX2;
    if (i < SZ_WH2){ transw1< 576,256, 64>(Wh2, Wht2, i); return; } i -= SZ_WH2;
    if (i < SZ_WX3){ transw1< 576,128, 32>(Wx3, Wxt3, i); return; } i -= SZ_WX3;
    if (i < SZ_WH3){ transw1< 288,128, 32>(Wh3, Wht3, i); }
}

// ---------------------------------------------------------------------------
// convx: implicit-im2col GEMM, bf16 MFMA, no LDS/barriers. 64x64 wg tile,
// 4 waves of 32x32 (2x2 MFMA frags). Zx out fp32 [M][N'] gate-interleaved
// (n' = co*4+g), bias added. launch_bounds(256,2): ~256 VGPR for deep
// load pipelining of the fully-unrolled tap/ci loops.
// ---------------------------------------------------------------------------
template<int CI, int CO>
__global__ __launch_bounds__(256, 2) void convx_mfma(
    const ushort* __restrict__ Abf, const ushort* __restrict__ Wt,
    const float* __restrict__ bias, float* __restrict__ Zx,
    int H, int Wd)
{
    constexpr int K = 9 * CI;
    constexpr int N = 4 * CO;

    const int tid = threadIdx.x;
    const int m0 = blockIdx.x * 64, n0 = blockIdx.y * 64;
    const int lane = tid & 63, wave = tid >> 6;
    const int wm = wave >> 1, wn = wave & 1;
    const int quad = lane >> 4, l16 = lane & 15;
    const int HW = H * Wd;

    int py[2], px[2], pbt[2];
    #pragma unroll
    for (int mt = 0; mt < 2; ++mt){
        const int p = m0 + wm * 32 + mt * 16 + l16;
        pbt[mt] = p / HW;
        const int rem = p - pbt[mt] * HW;
        py[mt] = rem / Wd; px[mt] = rem - (rem / Wd) * Wd;
    }
    const ushort* bp[2];
    #pragma unroll
    for (int nt = 0; nt < 2; ++nt)
        bp[nt] = &Wt[(size_t)(n0 + wn * 32 + nt * 16 + l16) * K + quad * 8];

    f32x4 acc[2][2] = {};

    #pragma unroll
    for (int tap = 0; tap < 9; ++tap){
        const int kh = tap / 3, kw = tap - (tap / 3) * 3;
        const ushort* ap[2]; bool va[2];
        #pragma unroll
        for (int mt = 0; mt < 2; ++mt){
            const int yy = py[mt] + kh - 1, xx = px[mt] + kw - 1;
            va[mt] = (yy >= 0 && yy < H && xx >= 0 && xx < Wd);
            ap[mt] = &Abf[((size_t)(pbt[mt] * H + (va[mt] ? yy : 0)) * Wd + (va[mt] ? xx : 0)) * CI + quad * 8];
        }
        #pragma unroll
        for (int ci0 = 0; ci0 < CI; ci0 += 32){
            s16x8 af[2], bf2[2];
            #pragma unroll
            for (int mt = 0; mt < 2; ++mt){
                s16x8 v = *(const s16x8*)(ap[mt] + ci0);
                af[mt] = va[mt] ? v : (s16x8)0;
            }
            #pragma unroll
            for (int nt = 0; nt < 2; ++nt)
                bf2[nt] = *(const s16x8*)(bp[nt] + tap * CI + ci0);
            #pragma unroll
            for (int mt = 0; mt < 2; ++mt)
                #pragma unroll
                for (int nt = 0; nt < 2; ++nt)
                    acc[mt][nt] = __builtin_amdgcn_mfma_f32_16x16x32_bf16(af[mt], bf2[nt], acc[mt][nt], 0, 0, 0);
        }
    }

    #pragma unroll
    for (int mt = 0; mt < 2; ++mt){
        #pragma unroll
        for (int nt = 0; nt < 2; ++nt){
            const int col = n0 + wn * 32 + nt * 16 + l16;      // interleaved col co*4+g
            const float bv = bias[(col & 3) * CO + (col >> 2)];
            #pragma unroll
            for (int r = 0; r < 4; ++r){
                const int row = m0 + wm * 32 + mt * 16 + quad * 4 + r;
                Zx[(size_t)row * N + col] = acc[mt][nt][r] + bv;
            }
        }
    }
}

// ---------------------------------------------------------------------------
// One LSTM timestep, one 32x32 tile per wg, conv K-loop SPLIT ACROSS THE 4
// WAVES (LDS reduce), epilogue fused (gates + BN + 2x2 upsample).
// FIRST=1 (t==0): h0=0, c0=0 -> conv and cst read skipped entirely.
// ---------------------------------------------------------------------------
template<int CO, int OUT_BF16, int FIRST>
__global__ __launch_bounds__(256, 2) void step_split(
    const float* __restrict__ Zx, const ushort* __restrict__ Wht,
    const ushort* __restrict__ hprev, ushort* __restrict__ hnew,
    float* __restrict__ cst,
    const float* __restrict__ gamma, const float* __restrict__ beta,
    const float* __restrict__ mmean, const float* __restrict__ mvar,
    void* __restrict__ outp, int H, int Wd, int t)
{
    constexpr int K = 9 * CO;
    constexpr int N4 = 4 * CO;
    constexpr int KITERS = K / 32;
    constexpr int CPT = CO / 32;   // k-chunks per tap

    __shared__ float Zs[4][32][36];   // per-wave K-partials (18.4 KB)

    const int tid = threadIdx.x;
    const int m0 = blockIdx.x * 32, n0 = blockIdx.y * 32;
    const int lane = tid & 63, wave = tid >> 6;
    const int quad = lane >> 4, l16 = lane & 15;
    const int HW = H * Wd;
    const int W2 = 2 * Wd;

    if (!FIRST){
        f32x4 acc[2][2] = {};
        int py[2], px[2], pb[2];
        #pragma unroll
        for (int mt = 0; mt < 2; ++mt){
            const int p = m0 + mt * 16 + l16;
            pb[mt] = p / HW;
            const int rem = p - pb[mt] * HW;
            py[mt] = rem / Wd; px[mt] = rem - (rem / Wd) * Wd;
        }
        const ushort* bp[2];
        #pragma unroll
        for (int nt = 0; nt < 2; ++nt)
            bp[nt] = &Wht[(size_t)(n0 + nt * 16 + l16) * K + quad * 8];

        for (int it = wave; it < KITERS; it += 4){
            const int tap = it / CPT;
            const int ci0 = (it - tap * CPT) * 32;
            const int kh = tap / 3, kw = tap - (tap / 3) * 3;
            s16x8 af[2], bf2[2];
            #pragma unroll
            for (int mt = 0; mt < 2; ++mt){
                const int yy = py[mt] + kh - 1, xx = px[mt] + kw - 1;
                const bool va = (yy >= 0 && yy < H && xx >= 0 && xx < Wd);
                s16x8 v = *(const s16x8*)&hprev[((size_t)(pb[mt] * H + (va ? yy : 0)) * Wd + (va ? xx : 0)) * CO + ci0 + quad * 8];
                af[mt] = va ? v : (s16x8)0;
            }
            #pragma unroll
            for (int nt = 0; nt < 2; ++nt)
                bf2[nt] = *(const s16x8*)(bp[nt] + tap * CO + ci0);
            #pragma unroll
            for (int mt = 0; mt < 2; ++mt)
                #pragma unroll
                for (int nt = 0; nt < 2; ++nt)
                    acc[mt][nt] = __builtin_amdgcn_mfma_f32_16x16x32_bf16(af[mt], bf2[nt], acc[mt][nt], 0, 0, 0);
        }

        // stash per-wave partials
        #pragma unroll
        for (int mt = 0; mt < 2; ++mt)
            #pragma unroll
            for (int nt = 0; nt < 2; ++nt)
                #pragma unroll
                for (int r = 0; r < 4; ++r)
                    Zs[wave][mt * 16 + quad * 4 + r][nt * 16 + l16] = acc[mt][nt][r];
        __syncthreads();
    }

    // epilogue: 32 pixels x 8 co (one (pixel,co) per thread; 4 gates)
    const int pp = tid >> 3, lc = tid & 7;
    const int m = m0 + pp;
    const int b2 = m / HW; const int rr = m - b2 * HW;
    const int y2 = rr / Wd, x2 = rr - (rr / Wd) * Wd;
    const int co = (n0 >> 2) + lc;

    const size_t zrow = (size_t)(b2 * TSTEPS + t) * HW + rr;
    const float4 zx = *(const float4*)&Zx[zrow * N4 + n0 + lc * 4];

    float zi = zx.x, zf = zx.y, zg = zx.z, zo = zx.w;
    if (!FIRST){
        const float4 s0 = *(const float4*)&Zs[0][pp][lc * 4];
        const float4 s1 = *(const float4*)&Zs[1][pp][lc * 4];
        const float4 s2 = *(const float4*)&Zs[2][pp][lc * 4];
        const float4 s3 = *(const float4*)&Zs[3][pp][lc * 4];
        zi += s0.x + s1.x + s2.x + s3.x;
        zf += s0.y + s1.y + s2.y + s3.y;
        zg += s0.z + s1.z + s2.z + s3.z;
        zo += s0.w + s1.w + s2.w + s3.w;
    }

    const float iv = hsig(zi), fv = hsig(zf);
    const float gv = tanhf(zg), ov = hsig(zo);
    const float cold = FIRST ? 0.0f : cst[(size_t)m * CO + co];
    const float cn = fv * cold + iv * gv;
    cst[(size_t)m * CO + co] = cn;
    const float h = ov * tanhf(cn);
    hnew[(size_t)m * CO + co] = f2bf(h);

    const float bnv = (h - mmean[co]) * rsqrtf(mvar[co] + 1e-3f) * gamma[co] + beta[co];
    const size_t ob = ((size_t)(b2 * TSTEPS + t) * 2 * H + 2 * y2) * W2 + 2 * x2;
    if (OUT_BF16){
        ushort* o = (ushort*)outp; const ushort hv = f2bf(bnv);
        o[ob * CO + co] = hv; o[(ob + 1) * CO + co] = hv;
        o[(ob + W2) * CO + co] = hv; o[(ob + W2 + 1) * CO + co] = hv;
    } else {
        float* o = (float*)outp;
        o[ob * CO + co] = bnv; o[(ob + 1) * CO + co] = bnv;
        o[(ob + W2) * CO + co] = bnv; o[(ob + W2 + 1) * CO + co] = bnv;
    }
}

template<int CI, int CO, int OUT_BF16>
static void run_block(const ushort* xbf, const ushort* Wxt, const ushort* Wht, const float* bias,
                      const float* g, const float* be, const float* mm, const float* mv,
                      float* Zx, ushort* hA, ushort* hB, float* cbuf, void* out,
                      int H, int W, hipStream_t stream)
{
    const int M = BATCH * TSTEPS * H * W;
    dim3 gx(M / 64, (4 * CO) / 64);
    convx_mfma<CI, CO><<<gx, 256, 0, stream>>>(xbf, Wxt, bias, Zx, H, W);

    dim3 gs((BATCH * H * W) / 32, (4 * CO) / 32);
    for (int t = 0; t < TSTEPS; ++t){
        const ushort* hp = (t & 1) ? hB : hA;
        ushort* hn = (t & 1) ? hA : hB;
        if (t == 0)
            step_split<CO, OUT_BF16, 1><<<gs, 256, 0, stream>>>(Zx, Wht, hp, hn, cbuf, g, be, mm, mv, out, H, W, t);
        else
            step_split<CO, OUT_BF16, 0><<<gs, 256, 0, stream>>>(Zx, Wht, hp, hn, cbuf, g, be, mm, mv, out, H, W, t);
    }
}

extern "C" void kernel_launch(void* const* d_in, const int* in_sizes, int n_in,
                              void* d_out, int out_size, void* d_ws, size_t ws_size,
                              hipStream_t stream) {
    const float* x   = (const float*)d_in[0];
    const float* Wx1 = (const float*)d_in[1];  const float* Wh1 = (const float*)d_in[2];
    const float* b1  = (const float*)d_in[3];  const float* g1  = (const float*)d_in[4];
    const float* be1 = (const float*)d_in[5];  const float* mm1 = (const float*)d_in[6];
    const float* mv1 = (const float*)d_in[7];
    const float* Wx2 = (const float*)d_in[8];  const float* Wh2 = (const float*)d_in[9];
    const float* b2  = (const float*)d_in[10]; const float* g2  = (const float*)d_in[11];
    const float* be2 = (const float*)d_in[12]; const float* mm2 = (const float*)d_in[13];
    const float* mv2 = (const float*)d_in[14];
    const float* Wx3 = (const float*)d_in[15]; const float* Wh3 = (const float*)d_in[16];
    const float* b3  = (const float*)d_in[17]; const float* g3  = (const float*)d_in[18];
    const float* be3 = (const float*)d_in[19]; const float* mm3 = (const float*)d_in[20];
    const float* mv3 = (const float*)d_in[21];

    char* ws = (char*)d_ws;
    size_t off = 0;
    auto alloc = [&](size_t bytes) { char* p = ws + off; off += (bytes + 255) & ~(size_t)255; return p; };

    float*  Zx   = (float*)alloc(8388608ull * 4);      // max Zx (block3: 65536*128)
    float*  cbuf = (float*)alloc(262144ull * 4);       // max c (block3: 8192*32)
    ushort* xbf  = (ushort*)alloc(786432ull * 2);
    ushort* x2   = (ushort*)alloc(2097152ull * 2);     // block1 out (bf16)
    ushort* x3   = (ushort*)alloc(4194304ull * 2);     // block2 out (bf16)
    ushort* hA   = (ushort*)alloc(262144ull * 2);
    ushort* hB   = (ushort*)alloc(262144ull * 2);
    ushort* Wxt1 = (ushort*)alloc(884736ull * 2);
    ushort* Wxt2 = (ushort*)alloc(294912ull * 2);
    ushort* Wxt3 = (ushort*)alloc(73728ull * 2);
    ushort* Wht1 = (ushort*)alloc(589824ull * 2);
    ushort* Wht2 = (ushort*)alloc(147456ull * 2);
    ushort* Wht3 = (ushort*)alloc(36864ull * 2);

    prep_kernel<<<(SZ_PREP + 255) / 256, 256, 0, stream>>>(
        x, Wx1, Wh1, Wx2, Wh2, Wx3, Wh3,
        xbf, Wxt1, Wht1, Wxt2, Wht2, Wxt3, Wht3);

    run_block<192, 128, 1>(xbf, Wxt1, Wht1, b1, g1, be1, mm1, mv1, Zx, hA, hB, cbuf, x2, 16, 16, stream);
    run_block<128,  64, 1>(x2,  Wxt2, Wht2, b2, g2, be2, mm2, mv2, Zx, hA, hB, cbuf, x3, 32, 32, stream);
    run_block< 64,  32, 0>(x3,  Wxt3, Wht3, b3, g3, be3, mm3, mv3, Zx, hA, hB, cbuf, d_out, 64, 64, stream);
}

// Round 9
// 459.262 us; speedup vs baseline: 3.7686x; 1.0005x over previous
//
#include <hip/hip_runtime.h>
#include <math.h>

#define BATCH 2
#define TSTEPS 8

typedef __attribute__((ext_vector_type(8))) short s16x8;   // 8 bf16 (4 VGPRs)
typedef __attribute__((ext_vector_type(4))) float f32x4;   // MFMA accum

__device__ __forceinline__ float hsig(float v){ return fminf(fmaxf(0.2f*v+0.5f,0.f),1.f); }

__device__ __forceinline__ ushort f2bf(float f){
    uint u = __builtin_bit_cast(uint, f);
    u = (u + 0x7FFFu + ((u >> 16) & 1u)) >> 16;   // round-to-nearest-even
    return (ushort)u;
}
__device__ __forceinline__ uint pack2bf(float lo, float hi){
    return (uint)f2bf(lo) | ((uint)f2bf(hi) << 16);
}

// ---------------- fused prep: x cast + 6 gate-interleaved weight transposes ----
template<int K,int N,int Co>
__device__ __forceinline__ void transw1(const float* __restrict__ W, ushort* __restrict__ Wt, int j){
    int n = j / K, k = j - n * K;
    int g = n & 3, co = n >> 2;            // dest row n' = co*4+g
    Wt[j] = f2bf(W[(size_t)k * N + g * Co + co]);
}

#define SZ_X    786432
#define SZ_WX1  884736
#define SZ_WH1  589824
#define SZ_WX2  294912
#define SZ_WH2  147456
#define SZ_WX3  73728
#define SZ_WH3  36864
#define SZ_PREP (SZ_X+SZ_WX1+SZ_WH1+SZ_WX2+SZ_WH2+SZ_WX3+SZ_WH3)

__global__ void prep_kernel(const float* __restrict__ x,
    const float* __restrict__ Wx1, const float* __restrict__ Wh1,
    const float* __restrict__ Wx2, const float* __restrict__ Wh2,
    const float* __restrict__ Wx3, const float* __restrict__ Wh3,
    ushort* __restrict__ xbf,
    ushort* __restrict__ Wxt1, ushort* __restrict__ Wht1,
    ushort* __restrict__ Wxt2, ushort* __restrict__ Wht2,
    ushort* __restrict__ Wxt3, ushort* __restrict__ Wht3)
{
    int i = blockIdx.x * 256 + threadIdx.x;
    if (i < SZ_X){ xbf[i] = f2bf(x[i]); return; } i -= SZ_X;
    if (i < SZ_WX1){ transw1<1728,512,128>(Wx1, Wxt1, i); return; } i -= SZ_WX1;
    if (i < SZ_WH1){ transw1<1152,512,128>(Wh1, Wht1, i); return; } i -= SZ_WH1;
    if (i < SZ_WX2){ transw1<1152,256, 64>(Wx2, Wxt2, i); return; } i -= SZ_WX2;
    if (i < SZ_WH2){ transw1< 576,256, 64>(Wh2, Wht2, i); return; } i -= SZ_WH2;
    if (i < SZ_WX3){ transw1< 576,128, 32>(Wx3, Wxt3, i); return; } i -= SZ_WX3;
    if (i < SZ_WH3){ transw1< 288,128, 32>(Wh3, Wht3, i); }
}

// ---------------------------------------------------------------------------
// convx: implicit-im2col GEMM, bf16 MFMA. 64x64 wg tile, 4 waves of 32x32.
// K-loop: register depth-2 prefetch (3-slot rotation, no LDS/barriers in loop)
// -> compiler keeps ~8 loads in flight (vmcnt(N) waits, not vmcnt(0)).
// Epilogue: LDS transpose -> coalesced float4 stores of Zx (gate-interleaved).
// ---------------------------------------------------------------------------
template<int CI, int CO>
__global__ __launch_bounds__(256) void convx_mfma(
    const ushort* __restrict__ Abf, const ushort* __restrict__ Wt,
    const float* __restrict__ bias, float* __restrict__ Zx,
    int H, int Wd)
{
    constexpr int K = 9 * CI;
    constexpr int N = 4 * CO;
    constexpr int CPT = CI / 32;
    constexpr int ITERS = K / 32;

    __shared__ float Zsc[64][68];

    const int tid = threadIdx.x;
    const int m0 = blockIdx.x * 64, n0 = blockIdx.y * 64;
    const int lane = tid & 63, wave = tid >> 6;
    const int wm = wave >> 1, wn = wave & 1;
    const int quad = lane >> 4, l16 = lane & 15;
    const int HW = H * Wd;

    int py[2], px[2], pbt[2];
    #pragma unroll
    for (int mt = 0; mt < 2; ++mt){
        const int p = m0 + wm * 32 + mt * 16 + l16;
        pbt[mt] = p / HW;
        const int rem = p - pbt[mt] * HW;
        py[mt] = rem / Wd; px[mt] = rem - (rem / Wd) * Wd;
    }
    const ushort* bp[2];
    #pragma unroll
    for (int nt = 0; nt < 2; ++nt)
        bp[nt] = &Wt[(size_t)(n0 + wn * 32 + nt * 16 + l16) * K + quad * 8];

    auto loadF = [&](int it, s16x8 (&af)[2], s16x8 (&bf2)[2]){
        const int tap = it / CPT, ci0 = (it - tap * CPT) * 32;
        const int kh = tap / 3, kw = tap - (tap / 3) * 3;
        #pragma unroll
        for (int mt = 0; mt < 2; ++mt){
            const int yy = py[mt] + kh - 1, xx = px[mt] + kw - 1;
            const bool va = (yy >= 0 && yy < H && xx >= 0 && xx < Wd);
            s16x8 v = *(const s16x8*)&Abf[((size_t)(pbt[mt] * H + (va ? yy : 0)) * Wd + (va ? xx : 0)) * CI + ci0 + quad * 8];
            af[mt] = va ? v : (s16x8)0;
        }
        #pragma unroll
        for (int nt = 0; nt < 2; ++nt)
            bf2[nt] = *(const s16x8*)(bp[nt] + tap * CI + ci0);
    };

    s16x8 afq[3][2], bfq[3][2];
    loadF(0, afq[0], bfq[0]);
    loadF(1, afq[1], bfq[1]);

    f32x4 acc[2][2] = {};

    #pragma unroll
    for (int it = 0; it < ITERS; ++it){
        if (it + 2 < ITERS) loadF(it + 2, afq[(it + 2) % 3], bfq[(it + 2) % 3]);
        s16x8 (&ca)[2] = afq[it % 3];
        s16x8 (&cb)[2] = bfq[it % 3];
        #pragma unroll
        for (int mt = 0; mt < 2; ++mt)
            #pragma unroll
            for (int nt = 0; nt < 2; ++nt)
                acc[mt][nt] = __builtin_amdgcn_mfma_f32_16x16x32_bf16(ca[mt], cb[nt], acc[mt][nt], 0, 0, 0);
    }

    // stash (+bias) into LDS, then coalesced float4 stores
    #pragma unroll
    for (int mt = 0; mt < 2; ++mt){
        #pragma unroll
        for (int nt = 0; nt < 2; ++nt){
            const int col = n0 + wn * 32 + nt * 16 + l16;
            const float bv = bias[(col & 3) * CO + (col >> 2)];
            #pragma unroll
            for (int r = 0; r < 4; ++r)
                Zsc[wm * 32 + mt * 16 + quad * 4 + r][wn * 32 + nt * 16 + l16] = acc[mt][nt][r] + bv;
        }
    }
    __syncthreads();

    const int sr = tid >> 4, sc = (tid & 15) << 2;
    #pragma unroll
    for (int rr4 = 0; rr4 < 4; ++rr4){
        const int row = rr4 * 16 + sr;
        float4 v = *(float4*)&Zsc[row][sc];
        *(float4*)&Zx[(size_t)(m0 + row) * N + n0 + sc] = v;
    }
}

// ---------------------------------------------------------------------------
// One LSTM timestep, 32x32 tile/wg, conv K-loop split across 4 waves with
// register depth-2 prefetch; LDS reduce; fused gates+BN+2x2-upsample epilogue
// with LDS-staged coalesced output stores.
// FIRST=1 (t==0): h0=0, c0=0 -> conv and cst read skipped.
// ---------------------------------------------------------------------------
template<int CO, int OUT_BF16, int FIRST>
__global__ __launch_bounds__(256) void step_split(
    const float* __restrict__ Zx, const ushort* __restrict__ Wht,
    const ushort* __restrict__ hprev, ushort* __restrict__ hnew,
    float* __restrict__ cst,
    const float* __restrict__ gamma, const float* __restrict__ beta,
    const float* __restrict__ mmean, const float* __restrict__ mvar,
    void* __restrict__ outp, int H, int Wd, int t)
{
    constexpr int K = 9 * CO;
    constexpr int N4 = 4 * CO;
    constexpr int KITERS = K / 32;
    constexpr int CPT = CO / 32;
    constexpr int MAXJ = (KITERS + 3) / 4;

    __shared__ float Zs[4][32][36];   // per-wave K-partials
    __shared__ float Hs[32][8];       // bn result stash for coalesced out-store

    const int tid = threadIdx.x;
    const int m0 = blockIdx.x * 32, n0 = blockIdx.y * 32;
    const int lane = tid & 63, wave = tid >> 6;
    const int quad = lane >> 4, l16 = lane & 15;
    const int HW = H * Wd;
    const int W2 = 2 * Wd;

    if (!FIRST){
        f32x4 acc[2][2] = {};
        int py[2], px[2], pb[2];
        #pragma unroll
        for (int mt = 0; mt < 2; ++mt){
            const int p = m0 + mt * 16 + l16;
            pb[mt] = p / HW;
            const int rem = p - pb[mt] * HW;
            py[mt] = rem / Wd; px[mt] = rem - (rem / Wd) * Wd;
        }
        const ushort* bp[2];
        #pragma unroll
        for (int nt = 0; nt < 2; ++nt)
            bp[nt] = &Wht[(size_t)(n0 + nt * 16 + l16) * K + quad * 8];

        auto loadF = [&](int it, s16x8 (&af)[2], s16x8 (&bf2)[2]){
            const int tap = it / CPT, ci0 = (it - tap * CPT) * 32;
            const int kh = tap / 3, kw = tap - (tap / 3) * 3;
            #pragma unroll
            for (int mt = 0; mt < 2; ++mt){
                const int yy = py[mt] + kh - 1, xx = px[mt] + kw - 1;
                const bool va = (yy >= 0 && yy < H && xx >= 0 && xx < Wd);
                s16x8 v = *(const s16x8*)&hprev[((size_t)(pb[mt] * H + (va ? yy : 0)) * Wd + (va ? xx : 0)) * CO + ci0 + quad * 8];
                af[mt] = va ? v : (s16x8)0;
            }
            #pragma unroll
            for (int nt = 0; nt < 2; ++nt)
                bf2[nt] = *(const s16x8*)(bp[nt] + tap * CO + ci0);
        };

        s16x8 afq[3][2], bfq[3][2];
        if (wave < KITERS)     loadF(wave,     afq[0], bfq[0]);
        if (wave + 4 < KITERS) loadF(wave + 4, afq[1], bfq[1]);

        #pragma unroll
        for (int j = 0; j < MAXJ; ++j){
            const int it = wave + 4 * j;
            if (it < KITERS){
                const int itn = wave + 4 * (j + 2);
                if (itn < KITERS) loadF(itn, afq[(j + 2) % 3], bfq[(j + 2) % 3]);
                s16x8 (&ca)[2] = afq[j % 3];
                s16x8 (&cb)[2] = bfq[j % 3];
                #pragma unroll
                for (int mt = 0; mt < 2; ++mt)
                    #pragma unroll
                    for (int nt = 0; nt < 2; ++nt)
                        acc[mt][nt] = __builtin_amdgcn_mfma_f32_16x16x32_bf16(ca[mt], cb[nt], acc[mt][nt], 0, 0, 0);
            }
        }

        #pragma unroll
        for (int mt = 0; mt < 2; ++mt)
            #pragma unroll
            for (int nt = 0; nt < 2; ++nt)
                #pragma unroll
                for (int r = 0; r < 4; ++r)
                    Zs[wave][mt * 16 + quad * 4 + r][nt * 16 + l16] = acc[mt][nt][r];
        __syncthreads();
    }

    // gates: 32 pixels x 8 co, one (pixel,co) per thread
    {
        const int pp = tid >> 3, lc = tid & 7;
        const int m = m0 + pp;
        const int b2 = m / HW; const int rr = m - b2 * HW;
        const int co = (n0 >> 2) + lc;

        const size_t zrow = (size_t)(b2 * TSTEPS + t) * HW + rr;
        const float4 zx = *(const float4*)&Zx[zrow * N4 + n0 + lc * 4];

        float zi = zx.x, zf = zx.y, zg = zx.z, zo = zx.w;
        if (!FIRST){
            const float4 s0 = *(const float4*)&Zs[0][pp][lc * 4];
            const float4 s1 = *(const float4*)&Zs[1][pp][lc * 4];
            const float4 s2 = *(const float4*)&Zs[2][pp][lc * 4];
            const float4 s3 = *(const float4*)&Zs[3][pp][lc * 4];
            zi += s0.x + s1.x + s2.x + s3.x;
            zf += s0.y + s1.y + s2.y + s3.y;
            zg += s0.z + s1.z + s2.z + s3.z;
            zo += s0.w + s1.w + s2.w + s3.w;
        }

        const float iv = hsig(zi), fv = hsig(zf);
        const float gv = tanhf(zg), ov = hsig(zo);
        const float cold = FIRST ? 0.0f : cst[(size_t)m * CO + co];
        const float cn = fv * cold + iv * gv;
        cst[(size_t)m * CO + co] = cn;
        const float h = ov * tanhf(cn);
        hnew[(size_t)m * CO + co] = f2bf(h);

        Hs[pp][lc] = (h - mmean[co]) * rsqrtf(mvar[co] + 1e-3f) * gamma[co] + beta[co];
    }
    __syncthreads();

    // coalesced upsampled store: 32 px * 2y * 2x * 8co
    const int spx = tid >> 3;                 // source pixel 0..31
    const int m = m0 + spx;
    const int b2 = m / HW; const int rr = m - b2 * HW;
    const int y2 = rr / Wd, x2 = rr - (rr / Wd) * Wd;
    const size_t obase = ((size_t)(b2 * TSTEPS + t) * 2 * H + 2 * y2) * W2 + 2 * x2;

    if (OUT_BF16){
        // thread q = tid&7: ypos=q>>2, xpos=(q>>1)&1, active half=q&1==0 writes uint4 (8 bf16)
        const int q = tid & 7;
        if ((q & 1) == 0){
            const int ypos = q >> 2, xpos = (q >> 1) & 1;
            const float* hsrc = &Hs[spx][0];
            uint4 v;
            v.x = pack2bf(hsrc[0], hsrc[1]); v.y = pack2bf(hsrc[2], hsrc[3]);
            v.z = pack2bf(hsrc[4], hsrc[5]); v.w = pack2bf(hsrc[6], hsrc[7]);
            ushort* o = (ushort*)outp;
            const size_t ob = obase + (size_t)ypos * W2 + xpos;
            *(uint4*)&o[ob * CO + (n0 >> 2)] = v;
        }
    } else {
        const int q = tid & 7;
        const int ypos = q >> 2, xpos = (q >> 1) & 1, half = q & 1;
        float4 v = *(const float4*)&Hs[spx][half * 4];
        float* o = (float*)outp;
        const size_t ob = obase + (size_t)ypos * W2 + xpos;
        *(float4*)&o[ob * CO + (n0 >> 2) + half * 4] = v;
    }
}

template<int CI, int CO, int OUT_BF16>
static void run_block(const ushort* xbf, const ushort* Wxt, const ushort* Wht, const float* bias,
                      const float* g, const float* be, const float* mm, const float* mv,
                      float* Zx, ushort* hA, ushort* hB, float* cbuf, void* out,
                      int H, int W, hipStream_t stream)
{
    const int M = BATCH * TSTEPS * H * W;
    dim3 gx(M / 64, (4 * CO) / 64);
    convx_mfma<CI, CO><<<gx, 256, 0, stream>>>(xbf, Wxt, bias, Zx, H, W);

    dim3 gs((BATCH * H * W) / 32, (4 * CO) / 32);
    for (int t = 0; t < TSTEPS; ++t){
        const ushort* hp = (t & 1) ? hB : hA;
        ushort* hn = (t & 1) ? hA : hB;
        if (t == 0)
            step_split<CO, OUT_BF16, 1><<<gs, 256, 0, stream>>>(Zx, Wht, hp, hn, cbuf, g, be, mm, mv, out, H, W, t);
        else
            step_split<CO, OUT_BF16, 0><<<gs, 256, 0, stream>>>(Zx, Wht, hp, hn, cbuf, g, be, mm, mv, out, H, W, t);
    }
}

extern "C" void kernel_launch(void* const* d_in, const int* in_sizes, int n_in,
                              void* d_out, int out_size, void* d_ws, size_t ws_size,
                              hipStream_t stream) {
    const float* x   = (const float*)d_in[0];
    const float* Wx1 = (const float*)d_in[1];  const float* Wh1 = (const float*)d_in[2];
    const float* b1  = (const float*)d_in[3];  const float* g1  = (const float*)d_in[4];
    const float* be1 = (const float*)d_in[5];  const float* mm1 = (const float*)d_in[6];
    const float* mv1 = (const float*)d_in[7];
    const float* Wx2 = (const float*)d_in[8];  const float* Wh2 = (const float*)d_in[9];
    const float* b2  = (const float*)d_in[10]; const float* g2  = (const float*)d_in[11];
    const float* be2 = (const float*)d_in[12]; const float* mm2 = (const float*)d_in[13];
    const float* mv2 = (const float*)d_in[14];
    const float* Wx3 = (const float*)d_in[15]; const float* Wh3 = (const float*)d_in[16];
    const float* b3  = (const float*)d_in[17]; const float* g3  = (const float*)d_in[18];
    const float* be3 = (const float*)d_in[19]; const float* mm3 = (const float*)d_in[20];
    const float* mv3 = (const float*)d_in[21];

    char* ws = (char*)d_ws;
    size_t off = 0;
    auto alloc = [&](size_t bytes) { char* p = ws + off; off += (bytes + 255) & ~(size_t)255; return p; };

    float*  Zx   = (float*)alloc(8388608ull * 4);      // max Zx (block3: 65536*128)
    float*  cbuf = (float*)alloc(262144ull * 4);       // max c (block3: 8192*32)
    ushort* xbf  = (ushort*)alloc(786432ull * 2);
    ushort* x2   = (ushort*)alloc(2097152ull * 2);     // block1 out (bf16)
    ushort* x3   = (ushort*)alloc(4194304ull * 2);     // block2 out (bf16)
    ushort* hA   = (ushort*)alloc(262144ull * 2);
    ushort* hB   = (ushort*)alloc(262144ull * 2);
    ushort* Wxt1 = (ushort*)alloc(884736ull * 2);
    ushort* Wxt2 = (ushort*)alloc(294912ull * 2);
    ushort* Wxt3 = (ushort*)alloc(73728ull * 2);
    ushort* Wht1 = (ushort*)alloc(589824ull * 2);
    ushort* Wht2 = (ushort*)alloc(147456ull * 2);
    ushort* Wht3 = (ushort*)alloc(36864ull * 2);

    prep_kernel<<<(SZ_PREP + 255) / 256, 256, 0, stream>>>(
        x, Wx1, Wh1, Wx2, Wh2, Wx3, Wh3,
        xbf, Wxt1, Wht1, Wxt2, Wht2, Wxt3, Wht3);

    run_block<192, 128, 1>(xbf, Wxt1, Wht1, b1, g1, be1, mm1, mv1, Zx, hA, hB, cbuf, x2, 16, 16, stream);
    run_block<128,  64, 1>(x2,  Wxt2, Wht2, b2, g2, be2, mm2, mv2, Zx, hA, hB, cbuf, x3, 32, 32, stream);
    run_block< 64,  32, 0>(x3,  Wxt3, Wht3, b3, g3, be3, mm3, mv3, Zx, hA, hB, cbuf, d_out, 64, 64, stream);
}